// Round 1
// baseline (1549.443 us; speedup 1.0000x reference)
//
#include <hip/hip_runtime.h>

#define B_   16
#define C_   256
#define H_   48
#define W_   48
#define N_   (H_ * W_)   // 2304
#define KNN  8

#define TI 64
#define TJ 64
#define KC 16

// ---------------------------------------------------------------------------
// Kernel 1: transpose [B,C,N] -> [B,N,C]
// ---------------------------------------------------------------------------
__global__ __launch_bounds__(256) void k_transpose(const float* __restrict__ fm,
                                                   float* __restrict__ nodes) {
    __shared__ float tile[32][33];
    int b  = blockIdx.z;
    int n0 = blockIdx.x * 32;
    int c0 = blockIdx.y * 32;
    int tx = threadIdx.x;   // 0..31
    int ty = threadIdx.y;   // 0..7
    const float* src = fm + (size_t)b * C_ * N_;
    float* dst = nodes + (size_t)b * N_ * C_;
    #pragma unroll
    for (int cc = 0; cc < 32; cc += 8) {
        tile[cc + ty][tx] = src[(size_t)(c0 + cc + ty) * N_ + n0 + tx];
    }
    __syncthreads();
    #pragma unroll
    for (int nn = 0; nn < 32; nn += 8) {
        dst[(size_t)(n0 + nn + ty) * C_ + c0 + tx] = tile[tx][nn + ty];
    }
}

// ---------------------------------------------------------------------------
// Kernel 2: sq[b,n] = sum_c fm[b,c,n]^2   (coalesced over n)
// ---------------------------------------------------------------------------
__global__ __launch_bounds__(256) void k_sq(const float* __restrict__ fm,
                                            float* __restrict__ sq) {
    int b = blockIdx.y;
    int n = blockIdx.x * 256 + threadIdx.x;
    const float* src = fm + (size_t)b * C_ * N_ + n;
    float s = 0.f;
    for (int c = 0; c < C_; ++c) {
        float v = src[(size_t)c * N_];
        s = fmaf(v, v, s);
    }
    sq[b * N_ + n] = s;
}

// ---------------------------------------------------------------------------
// Kernel 3: fused Gram + d2 + running top-8 (smallest d2, ties -> lower index)
// d2(i,j) = sq[i] + sq[j] - 2*dot(x_i, x_j);  j == i excluded.
// Block: 256 threads, TI=64 rows, loops all TJ=64 j-tiles.
// ---------------------------------------------------------------------------
__global__ __launch_bounds__(256) void k_knn(const float* __restrict__ nodes,
                                             const float* __restrict__ sq,
                                             int* __restrict__ knn) {
    __shared__ float At[KC][TI];
    __shared__ float Bt[KC][TJ];
    __shared__ float d2t[TI][TJ + 2];
    __shared__ float sqi_s[TI];
    __shared__ float sqj_s[TJ];

    int b   = blockIdx.y;
    int i0  = blockIdx.x * TI;
    int tid = threadIdx.x;
    const float* Xb = nodes + (size_t)b * N_ * C_;

    int tx = tid & 15;        // i group
    int ty = tid >> 4;        // j group
    int ibase = tx * 4;
    int jbase = ty * 4;

    int lr = tid >> 2;          // load row 0..63
    int lk = (tid & 3) * 4;     // load k offset {0,4,8,12}

    if (tid < TI) sqi_s[tid] = sq[b * N_ + i0 + tid];

    float bestv[KNN];
    int   besti[KNN];
    #pragma unroll
    for (int k = 0; k < KNN; ++k) { bestv[k] = 3.4e38f; besti[k] = 0; }

    for (int j0 = 0; j0 < N_; j0 += TJ) {
        if (tid < TJ) sqj_s[tid] = sq[b * N_ + j0 + tid];

        float acc[4][4];
        #pragma unroll
        for (int a = 0; a < 4; ++a)
            #pragma unroll
            for (int bb = 0; bb < 4; ++bb) acc[a][bb] = 0.f;

        for (int k0 = 0; k0 < C_; k0 += KC) {
            float4 av = *(const float4*)&Xb[(size_t)(i0 + lr) * C_ + k0 + lk];
            float4 bv = *(const float4*)&Xb[(size_t)(j0 + lr) * C_ + k0 + lk];
            __syncthreads();   // protect previous chunk's reads (and d2t scan on first chunk)
            At[lk + 0][lr] = av.x; At[lk + 1][lr] = av.y;
            At[lk + 2][lr] = av.z; At[lk + 3][lr] = av.w;
            Bt[lk + 0][lr] = bv.x; Bt[lk + 1][lr] = bv.y;
            Bt[lk + 2][lr] = bv.z; Bt[lk + 3][lr] = bv.w;
            __syncthreads();
            #pragma unroll
            for (int kk = 0; kk < KC; ++kk) {
                float4 a4 = *(const float4*)&At[kk][ibase];
                float4 b4 = *(const float4*)&Bt[kk][jbase];
                float aa[4] = {a4.x, a4.y, a4.z, a4.w};
                float bbv[4] = {b4.x, b4.y, b4.z, b4.w};
                #pragma unroll
                for (int a = 0; a < 4; ++a)
                    #pragma unroll
                    for (int bb = 0; bb < 4; ++bb)
                        acc[a][bb] = fmaf(aa[a], bbv[bb], acc[a][bb]);
            }
        }

        __syncthreads();   // previous scan of d2t done (also covers sqj read ordering)
        #pragma unroll
        for (int a = 0; a < 4; ++a) {
            #pragma unroll
            for (int bb = 0; bb < 4; ++bb) {
                int il = ibase + a, jl = jbase + bb;
                float d2 = sqi_s[il] + sqj_s[jl] - 2.f * acc[a][bb];
                if (i0 + il == j0 + jl) d2 = 1e30f;   // exclude self
                d2t[il][jl] = d2;
            }
        }
        __syncthreads();

        if (tid < TI) {
            int r = tid;
            for (int jj = 0; jj < TJ; ++jj) {
                float v = d2t[r][jj];
                if (v < bestv[KNN - 1]) {     // strict: ties keep earlier (smaller) index
                    float cv = v; int ci = j0 + jj;
                    #pragma unroll
                    for (int p = 0; p < KNN; ++p) {
                        if (cv < bestv[p]) {
                            float tv = bestv[p]; bestv[p] = cv; cv = tv;
                            int tix = besti[p]; besti[p] = ci; ci = tix;
                        }
                    }
                }
            }
        }
    }

    if (tid < TI) {
        int* kr = knn + ((size_t)b * N_ + i0 + tid) * KNN;
        #pragma unroll
        for (int k = 0; k < KNN; ++k) kr[k] = besti[k];
    }
}

// ---------------------------------------------------------------------------
// Kernel 4: aggregate (grid 4-nbrs + 8 knn) mean + residual + LayerNorm(C)
//           + transposed write-out to [B,C,N]
// ---------------------------------------------------------------------------
__global__ __launch_bounds__(256) void k_agg_ln(const float* __restrict__ nodes,
                                                const int* __restrict__ knn,
                                                const float* __restrict__ gamma,
                                                const float* __restrict__ beta,
                                                float* __restrict__ out) {
    __shared__ float ytile[16][C_ + 1];
    __shared__ float red[8];

    int b   = blockIdx.y;
    int i0  = blockIdx.x * 16;
    int tid = threadIdx.x;   // channel c
    const float* Xb = nodes + (size_t)b * N_ * C_;
    float g  = gamma[tid];
    float be = beta[tid];

    for (int ii = 0; ii < 16; ++ii) {
        int i  = i0 + ii;
        int x_ = i % W_;
        int y_ = i / W_;
        float s = 0.f;
        int cnt = KNN;
        if (x_ > 0)      { s += Xb[(size_t)(i - 1)  * C_ + tid]; cnt++; }
        if (x_ < W_ - 1) { s += Xb[(size_t)(i + 1)  * C_ + tid]; cnt++; }
        if (y_ > 0)      { s += Xb[(size_t)(i - W_) * C_ + tid]; cnt++; }
        if (y_ < H_ - 1) { s += Xb[(size_t)(i + W_) * C_ + tid]; cnt++; }
        const int* kr = knn + ((size_t)b * N_ + i) * KNN;
        #pragma unroll
        for (int k = 0; k < KNN; ++k) s += Xb[(size_t)kr[k] * C_ + tid];

        float yv = s / (float)cnt + Xb[(size_t)i * C_ + tid];

        float rx = yv, ry = yv * yv;
        #pragma unroll
        for (int m = 32; m >= 1; m >>= 1) {
            rx += __shfl_xor(rx, m);
            ry += __shfl_xor(ry, m);
        }
        int wid = tid >> 6, lane = tid & 63;
        __syncthreads();   // protect red[] from previous iteration's readers
        if (lane == 0) { red[wid * 2] = rx; red[wid * 2 + 1] = ry; }
        __syncthreads();
        float S1 = red[0] + red[2] + red[4] + red[6];
        float S2 = red[1] + red[3] + red[5] + red[7];
        float mu  = S1 * (1.f / C_);
        float var = S2 * (1.f / C_) - mu * mu;
        float inv = rsqrtf(var + 1e-5f);
        ytile[ii][tid] = (yv - mu) * inv * g + be;
    }
    __syncthreads();

    // write out[b][c][i0..i0+15], c = tid  (16 contiguous floats per thread)
    float* op = out + (size_t)b * C_ * N_ + (size_t)tid * N_ + i0;
    float vv[16];
    #pragma unroll
    for (int ii = 0; ii < 16; ++ii) vv[ii] = ytile[ii][tid];
    #pragma unroll
    for (int q = 0; q < 4; ++q) {
        float4 w;
        w.x = vv[q * 4 + 0]; w.y = vv[q * 4 + 1];
        w.z = vv[q * 4 + 2]; w.w = vv[q * 4 + 3];
        *(float4*)&op[q * 4] = w;
    }
}

// ---------------------------------------------------------------------------
extern "C" void kernel_launch(void* const* d_in, const int* in_sizes, int n_in,
                              void* d_out, int out_size, void* d_ws, size_t ws_size,
                              hipStream_t stream) {
    const float* fm    = (const float*)d_in[0];
    const float* gamma = (const float*)d_in[1];
    const float* beta  = (const float*)d_in[2];
    float* out = (float*)d_out;

    char* ws = (char*)d_ws;
    float* nodes = (float*)ws;                                   // B*N*C f32 = 37.75 MB
    size_t off   = (size_t)B_ * N_ * C_ * sizeof(float);
    float* sq    = (float*)(ws + off);                           // B*N f32
    off += (size_t)B_ * N_ * sizeof(float);
    int*   knn   = (int*)(ws + off);                             // B*N*K i32

    k_transpose<<<dim3(N_ / 32, C_ / 32, B_), dim3(32, 8), 0, stream>>>(fm, nodes);
    k_sq<<<dim3(N_ / 256, B_), 256, 0, stream>>>(fm, sq);
    k_knn<<<dim3(N_ / TI, B_), 256, 0, stream>>>(nodes, sq, knn);
    k_agg_ln<<<dim3(N_ / 16, B_), 256, 0, stream>>>(nodes, knn, gamma, beta, out);
}

// Round 2
// 1300.403 us; speedup vs baseline: 1.1915x; 1.1915x over previous
//
#include <hip/hip_runtime.h>

#define B_   16
#define C_   256
#define H_   48
#define W_   48
#define N_   (H_ * W_)   // 2304
#define KNN  8

#define TI 128
#define TJ 64
#define KC 16
#define JSPLIT 4
#define NJT (N_ / TJ / JSPLIT)   // 9 j-tiles per block

// ---------------------------------------------------------------------------
// Kernel 1: transpose [B,C,N] -> [B,N,C]
// ---------------------------------------------------------------------------
__global__ __launch_bounds__(256) void k_transpose(const float* __restrict__ fm,
                                                   float* __restrict__ nodes) {
    __shared__ float tile[32][33];
    int b  = blockIdx.z;
    int n0 = blockIdx.x * 32;
    int c0 = blockIdx.y * 32;
    int tx = threadIdx.x;   // 0..31
    int ty = threadIdx.y;   // 0..7
    const float* src = fm + (size_t)b * C_ * N_;
    float* dst = nodes + (size_t)b * N_ * C_;
    #pragma unroll
    for (int cc = 0; cc < 32; cc += 8) {
        tile[cc + ty][tx] = src[(size_t)(c0 + cc + ty) * N_ + n0 + tx];
    }
    __syncthreads();
    #pragma unroll
    for (int nn = 0; nn < 32; nn += 8) {
        dst[(size_t)(n0 + nn + ty) * C_ + c0 + tx] = tile[tx][nn + ty];
    }
}

// ---------------------------------------------------------------------------
// Kernel 2: sq[b,n] = sum_c fm[b,c,n]^2
// ---------------------------------------------------------------------------
__global__ __launch_bounds__(256) void k_sq(const float* __restrict__ fm,
                                            float* __restrict__ sq) {
    int b = blockIdx.y;
    int n = blockIdx.x * 256 + threadIdx.x;
    const float* src = fm + (size_t)b * C_ * N_ + n;
    float s = 0.f;
    for (int c = 0; c < C_; ++c) {
        float v = src[(size_t)c * N_];
        s = fmaf(v, v, s);
    }
    sq[b * N_ + n] = s;
}

__device__ __forceinline__ bool lex_lt(float v, int i, float bv, int bi) {
    return (v < bv) || (v == bv && i < bi);
}

// ---------------------------------------------------------------------------
// Kernel 3: fused Gram + d2 + running top-8 over this block's j-range.
// TI=128 rows/block, 8x4 acc per thread, j split across JSPLIT blocks.
// Partial (v,idx) top-8 per row written to pv/pi for the merge kernel.
// ---------------------------------------------------------------------------
__global__ __launch_bounds__(256) void k_knn(const float* __restrict__ nodes,
                                             const float* __restrict__ sq,
                                             float* __restrict__ pv,
                                             int* __restrict__ pi) {
    __shared__ __align__(16) float At[KC][TI];      // 8 KB
    __shared__ __align__(16) float Bt[KC][TJ];      // 4 KB
    __shared__ __align__(16) float d2t[TI][TJ + 1]; // 33.3 KB (pad -> 2-way max on scan)
    __shared__ float sqi_s[TI];
    __shared__ float sqj_s[TJ];

    int b   = blockIdx.z;
    int i0  = blockIdx.x * TI;
    int js  = blockIdx.y;
    int tid = threadIdx.x;
    const float* Xb = nodes + (size_t)b * N_ * C_;

    int ti = tid & 15;          // i group: rows ti*8..ti*8+7
    int tj = tid >> 4;          // j group: cols tj*4..tj*4+3
    int arow  = tid >> 1, akoff = (tid & 1) * 8;
    int brow  = tid >> 2, bkoff = (tid & 3) * 4;
    int r = tid >> 1, half = tid & 1;   // scan assignment

    if (tid < TI) sqi_s[tid] = sq[b * N_ + i0 + tid];

    float bestv[KNN];
    int   besti[KNN];
    #pragma unroll
    for (int k = 0; k < KNN; ++k) { bestv[k] = 3.4e38f; besti[k] = 0x7fffffff; }

    for (int jt = 0; jt < NJT; ++jt) {
        int jg0 = (js * NJT + jt) * TJ;
        if (tid < TJ) sqj_s[tid] = sq[b * N_ + jg0 + tid];

        float acc[8][4];
        #pragma unroll
        for (int a = 0; a < 8; ++a)
            #pragma unroll
            for (int bb = 0; bb < 4; ++bb) acc[a][bb] = 0.f;

        for (int k0 = 0; k0 < C_; k0 += KC) {
            const float* ap = &Xb[(size_t)(i0 + arow) * C_ + k0 + akoff];
            float4 a0 = *(const float4*)ap;
            float4 a1 = *(const float4*)(ap + 4);
            float4 b4 = *(const float4*)&Xb[(size_t)(jg0 + brow) * C_ + k0 + bkoff];
            __syncthreads();   // prev chunk's At/Bt reads (and prev tile's d2t scan) done
            At[akoff + 0][arow] = a0.x; At[akoff + 1][arow] = a0.y;
            At[akoff + 2][arow] = a0.z; At[akoff + 3][arow] = a0.w;
            At[akoff + 4][arow] = a1.x; At[akoff + 5][arow] = a1.y;
            At[akoff + 6][arow] = a1.z; At[akoff + 7][arow] = a1.w;
            Bt[bkoff + 0][brow] = b4.x; Bt[bkoff + 1][brow] = b4.y;
            Bt[bkoff + 2][brow] = b4.z; Bt[bkoff + 3][brow] = b4.w;
            __syncthreads();
            #pragma unroll
            for (int kk = 0; kk < KC; ++kk) {
                float4 av0 = *(const float4*)&At[kk][ti * 8];
                float4 av1 = *(const float4*)&At[kk][ti * 8 + 4];
                float4 bv0 = *(const float4*)&Bt[kk][tj * 4];
                float aa[8] = {av0.x, av0.y, av0.z, av0.w, av1.x, av1.y, av1.z, av1.w};
                float bb_[4] = {bv0.x, bv0.y, bv0.z, bv0.w};
                #pragma unroll
                for (int a = 0; a < 8; ++a)
                    #pragma unroll
                    for (int bb = 0; bb < 4; ++bb)
                        acc[a][bb] = fmaf(aa[a], bb_[bb], acc[a][bb]);
            }
        }

        // d2 = sqi + sqj - 2*dot ; exclude self
        #pragma unroll
        for (int a = 0; a < 8; ++a) {
            #pragma unroll
            for (int bb = 0; bb < 4; ++bb) {
                int il = ti * 8 + a, jl = tj * 4 + bb;
                float d2 = sqi_s[il] + sqj_s[jl] - 2.f * acc[a][bb];
                if (i0 + il == jg0 + jl) d2 = 1e30f;
                d2t[il][jl] = d2;
            }
        }
        __syncthreads();

        // parallel scan: 2 threads per row, 32 cols each; running per-thread top-8
        {
            const float* drow = &d2t[r][half * 32];
            int jb = jg0 + half * 32;
            for (int s = 0; s < 32; ++s) {
                float v = drow[s];
                if (v < bestv[KNN - 1]) {   // strict <: ascending-j insertion keeps lower idx on ties
                    float cv = v; int ci = jb + s;
                    #pragma unroll
                    for (int p = 0; p < KNN; ++p) {
                        if (cv < bestv[p]) {
                            float tv = bestv[p]; bestv[p] = cv; cv = tv;
                            int tx2 = besti[p]; besti[p] = ci; ci = tx2;
                        }
                    }
                }
            }
        }
        // no barrier: next tile's first k-loop barrier protects d2t/sqj_s reuse
    }

    // in-block merge of the 2 half-lists per row -> partial top-8 for this j-split
    __syncthreads();
    float* cv = &At[0][0];          // [128][16] values (8 KB, At dead)
    int*   ci = (int*)&d2t[0][0];   // [128][16] indices (d2t dead)
    #pragma unroll
    for (int q = 0; q < KNN; ++q) {
        cv[r * 16 + half * 8 + q] = bestv[q];
        ci[r * 16 + half * 8 + q] = besti[q];
    }
    __syncthreads();
    if (tid < TI) {
        float mv[KNN]; int mi[KNN];
        #pragma unroll
        for (int k = 0; k < KNN; ++k) { mv[k] = 3.4e38f; mi[k] = 0x7fffffff; }
        for (int s = 0; s < 16; ++s) {
            float v = cv[tid * 16 + s]; int ix = ci[tid * 16 + s];
            if (lex_lt(v, ix, mv[KNN - 1], mi[KNN - 1])) {
                float cv2 = v; int ci2 = ix;
                #pragma unroll
                for (int p = 0; p < KNN; ++p) {
                    if (lex_lt(cv2, ci2, mv[p], mi[p])) {
                        float tv = mv[p]; mv[p] = cv2; cv2 = tv;
                        int tx2 = mi[p]; mi[p] = ci2; ci2 = tx2;
                    }
                }
            }
        }
        size_t base = (((size_t)b * N_ + i0 + tid) * JSPLIT + js) * KNN;
        #pragma unroll
        for (int q = 0; q < KNN; ++q) { pv[base + q] = mv[q]; pi[base + q] = mi[q]; }
    }
}

// ---------------------------------------------------------------------------
// Kernel 3b: merge JSPLIT partial top-8 lists per row -> final knn indices
// ---------------------------------------------------------------------------
__global__ __launch_bounds__(256) void k_merge(const float* __restrict__ pv,
                                               const int* __restrict__ pi,
                                               int* __restrict__ knn) {
    int t = blockIdx.x * 256 + threadIdx.x;   // row id b*N+i  (36864 = 144*256)
    float mv[KNN]; int mi[KNN];
    #pragma unroll
    for (int k = 0; k < KNN; ++k) { mv[k] = 3.4e38f; mi[k] = 0x7fffffff; }
    const float* v  = pv + (size_t)t * JSPLIT * KNN;
    const int*   ix = pi + (size_t)t * JSPLIT * KNN;
    for (int s = 0; s < JSPLIT * KNN; ++s) {
        float cv = v[s]; int ci = ix[s];
        if (lex_lt(cv, ci, mv[KNN - 1], mi[KNN - 1])) {
            #pragma unroll
            for (int p = 0; p < KNN; ++p) {
                if (lex_lt(cv, ci, mv[p], mi[p])) {
                    float tv = mv[p]; mv[p] = cv; cv = tv;
                    int tx2 = mi[p]; mi[p] = ci; ci = tx2;
                }
            }
        }
    }
    int* kr = knn + (size_t)t * KNN;
    #pragma unroll
    for (int q = 0; q < KNN; ++q) kr[q] = mi[q];
}

// ---------------------------------------------------------------------------
// Kernel 4: aggregate (grid 4-nbrs + 8 knn) mean + residual + LayerNorm(C)
//           + transposed write-out to [B,C,N]
// ---------------------------------------------------------------------------
__global__ __launch_bounds__(256) void k_agg_ln(const float* __restrict__ nodes,
                                                const int* __restrict__ knn,
                                                const float* __restrict__ gamma,
                                                const float* __restrict__ beta,
                                                float* __restrict__ out) {
    __shared__ float ytile[16][C_ + 1];
    __shared__ float red[8];

    int b   = blockIdx.y;
    int i0  = blockIdx.x * 16;
    int tid = threadIdx.x;   // channel c
    const float* Xb = nodes + (size_t)b * N_ * C_;
    float g  = gamma[tid];
    float be = beta[tid];

    for (int ii = 0; ii < 16; ++ii) {
        int i  = i0 + ii;
        int x_ = i % W_;
        int y_ = i / W_;
        float s = 0.f;
        int cnt = KNN;
        if (x_ > 0)      { s += Xb[(size_t)(i - 1)  * C_ + tid]; cnt++; }
        if (x_ < W_ - 1) { s += Xb[(size_t)(i + 1)  * C_ + tid]; cnt++; }
        if (y_ > 0)      { s += Xb[(size_t)(i - W_) * C_ + tid]; cnt++; }
        if (y_ < H_ - 1) { s += Xb[(size_t)(i + W_) * C_ + tid]; cnt++; }
        const int* kr = knn + ((size_t)b * N_ + i) * KNN;
        #pragma unroll
        for (int k = 0; k < KNN; ++k) s += Xb[(size_t)kr[k] * C_ + tid];

        float yv = s / (float)cnt + Xb[(size_t)i * C_ + tid];

        float rx = yv, ry = yv * yv;
        #pragma unroll
        for (int m = 32; m >= 1; m >>= 1) {
            rx += __shfl_xor(rx, m);
            ry += __shfl_xor(ry, m);
        }
        int wid = tid >> 6, lane = tid & 63;
        __syncthreads();
        if (lane == 0) { red[wid * 2] = rx; red[wid * 2 + 1] = ry; }
        __syncthreads();
        float S1 = red[0] + red[2] + red[4] + red[6];
        float S2 = red[1] + red[3] + red[5] + red[7];
        float mu  = S1 * (1.f / C_);
        float var = S2 * (1.f / C_) - mu * mu;
        float inv = rsqrtf(var + 1e-5f);
        ytile[ii][tid] = (yv - mu) * inv * g + be;
    }
    __syncthreads();

    float* op = out + (size_t)b * C_ * N_ + (size_t)tid * N_ + i0;
    float vv[16];
    #pragma unroll
    for (int ii = 0; ii < 16; ++ii) vv[ii] = ytile[ii][tid];
    #pragma unroll
    for (int q = 0; q < 4; ++q) {
        float4 w;
        w.x = vv[q * 4 + 0]; w.y = vv[q * 4 + 1];
        w.z = vv[q * 4 + 2]; w.w = vv[q * 4 + 3];
        *(float4*)&op[q * 4] = w;
    }
}

// ---------------------------------------------------------------------------
extern "C" void kernel_launch(void* const* d_in, const int* in_sizes, int n_in,
                              void* d_out, int out_size, void* d_ws, size_t ws_size,
                              hipStream_t stream) {
    const float* fm    = (const float*)d_in[0];
    const float* gamma = (const float*)d_in[1];
    const float* beta  = (const float*)d_in[2];
    float* out = (float*)d_out;

    char* ws = (char*)d_ws;
    size_t off = 0;
    float* nodes = (float*)(ws + off); off += (size_t)B_ * N_ * C_ * sizeof(float);      // 37.75 MB
    float* sq    = (float*)(ws + off); off += (size_t)B_ * N_ * sizeof(float);           // 0.14 MB
    int*   knn   = (int*)  (ws + off); off += (size_t)B_ * N_ * KNN * sizeof(int);       // 1.18 MB
    float* pv    = (float*)(ws + off); off += (size_t)B_ * N_ * JSPLIT * KNN * sizeof(float); // 4.7 MB
    int*   pi    = (int*)  (ws + off); off += (size_t)B_ * N_ * JSPLIT * KNN * sizeof(int);   // 4.7 MB

    k_transpose<<<dim3(N_ / 32, C_ / 32, B_), dim3(32, 8), 0, stream>>>(fm, nodes);
    k_sq<<<dim3(N_ / 256, B_), 256, 0, stream>>>(fm, sq);
    k_knn<<<dim3(N_ / TI, JSPLIT, B_), 256, 0, stream>>>(nodes, sq, pv, pi);
    k_merge<<<(B_ * N_) / 256, 256, 0, stream>>>(pv, pi, knn);
    k_agg_ln<<<dim3(N_ / 16, B_), 256, 0, stream>>>(nodes, knn, gamma, beta, out);
}